// Round 5
// baseline (32159.985 us; speedup 1.0000x reference)
//
#include <hip/hip_runtime.h>

typedef unsigned short u16;
typedef unsigned int u32;
typedef u16 u16x8 __attribute__((ext_vector_type(8)));
typedef u16 u16x4 __attribute__((ext_vector_type(4)));
typedef __bf16 bf16x8 __attribute__((ext_vector_type(8)));
typedef float f32x4 __attribute__((ext_vector_type(4)));
typedef float f32x2 __attribute__((ext_vector_type(2)));

#define B_ 64
#define T_ 256
#define D_ 256
#define H_ 1024
#define G4 4096
#define TC 64            // timesteps per chunk
#define MC 4096          // rows per chunk (B_*TC)
#define NCHUNK 4
#define RBLK 64          // k_rec blocks: 8 gate-groups x 8 batch-parts

// ---------- helpers ----------
__device__ __forceinline__ u16 f2bf(float x) {
  u32 u = __builtin_bit_cast(u32, x);
  u += 0x7fffu + ((u >> 16) & 1u);
  return (u16)(u >> 16);
}
__device__ __forceinline__ float bf2f(u16 h) {
  u32 u = ((u32)h) << 16;
  return __builtin_bit_cast(float, u);
}
__device__ __forceinline__ float sigmoidf_(float x) { return 1.f / (1.f + __expf(-x)); }

__device__ __forceinline__ f32x4 mfma16(u16x8 a, u16x8 b, f32x4 c) {
  return __builtin_amdgcn_mfma_f32_16x16x32_bf16(
      __builtin_bit_cast(bf16x8, a), __builtin_bit_cast(bf16x8, b), c, 0, 0, 0);
}

__device__ __forceinline__ void gl2lds16(const u16* g, u16* l) {
  __builtin_amdgcn_global_load_lds(
      (const __attribute__((address_space(1))) u32*)(const void*)g,
      (__attribute__((address_space(3))) u32*)(void*)l, 16, 0, 0);
}

// device-coherent (cross-XCD) 16B load / 4B store, bypassing non-coherent L2
__device__ __forceinline__ u16x8 load16_cc(const u16* p) {
  u16x8 v;
  asm volatile("global_load_dwordx4 %0, %1, off sc0 sc1" : "=v"(v) : "v"(p));
  return v;
}
__device__ __forceinline__ void store4_cc(u16* p, u32 v) {
  asm volatile("global_store_dword %0, %1, off sc0 sc1" :: "v"(p), "v"(v) : "memory");
}
__device__ __forceinline__ void waitcnt0() {
  asm volatile("s_waitcnt vmcnt(0)" ::: "memory");
}

// ---------- split fp32 -> (hi, lo) bf16 planes ----------
__global__ void k_split(const float* __restrict__ src, u16* __restrict__ hi,
                        u16* __restrict__ lo, int n4) {
  int i = blockIdx.x * 256 + threadIdx.x;
  if (i >= n4) return;
  const float4* s4 = (const float4*)src;
  float4 v = s4[i];
  u16 h0 = f2bf(v.x), h1 = f2bf(v.y), h2 = f2bf(v.z), h3 = f2bf(v.w);
  u16x4 hv = {h0, h1, h2, h3};
  u16x4 lv = {f2bf(v.x - bf2f(h0)), f2bf(v.y - bf2f(h1)),
              f2bf(v.z - bf2f(h2)), f2bf(v.w - bf2f(h3))};
  *(u16x4*)(hi + 4 * (size_t)i) = hv;
  *(u16x4*)(lo + 4 * (size_t)i) = lv;
}

// gather one time-chunk of xx ([B,T,D] -> [B*TC, D]) and split planes
__global__ void k_split_x(const float* __restrict__ xx, u16* __restrict__ hi,
                          u16* __restrict__ lo, int t0) {
  int i = blockIdx.x * 256 + threadIdx.x;   // over MC * D_/4
  if (i >= MC * (D_ / 4)) return;
  int row = i >> 6, c4 = i & 63;
  int b = row >> 6, tc = row & 63;
  const float4* s4 = (const float4*)xx;
  float4 v = s4[(size_t)(b * T_ + t0 + tc) * (D_ / 4) + c4];
  u16 h0 = f2bf(v.x), h1 = f2bf(v.y), h2 = f2bf(v.z), h3 = f2bf(v.w);
  u16x4 hv = {h0, h1, h2, h3};
  u16x4 lv = {f2bf(v.x - bf2f(h0)), f2bf(v.y - bf2f(h1)),
              f2bf(v.z - bf2f(h2)), f2bf(v.w - bf2f(h3))};
  *(u16x4*)(hi + 4 * (size_t)i) = hv;
  *(u16x4*)(lo + 4 * (size_t)i) = lv;
}

__global__ void k_addvec(const float* __restrict__ a, const float* __restrict__ b,
                         float* __restrict__ o, int n) {
  int i = blockIdx.x * 256 + threadIdx.x;
  if (i < n) o[i] = a[i] + b[i];
}

// ---------- split-precision GEMM: C[M,N] = A[M,K] * B[N,K]^T + bias (fp32 out) ----
// rec=0: standard C[m][n].  rec=1: k_rec layout
//   idx = ((g*8+p)*64 + t)*4096 + gate*1024 + bb*128 + u
//   where m = B*64+t (B=p*8+bb), n = gate*1024 + g*128 + u
__global__ __launch_bounds__(256, 2) void k_gemm3(
    const u16* __restrict__ Ah, const u16* __restrict__ Al,
    const u16* __restrict__ Bh, const u16* __restrict__ Bl,
    const float* __restrict__ bias, float* __restrict__ C,
    int M, int N, int K, int rec)
{
  __shared__ __attribute__((aligned(16))) u16 sAh[4096];
  __shared__ __attribute__((aligned(16))) u16 sAl[4096];
  __shared__ __attribute__((aligned(16))) u16 sBh[4096];
  __shared__ __attribute__((aligned(16))) u16 sBl[4096];

  const int tid = threadIdx.x;
  const int lane = tid & 63;
  const int wv = tid >> 6;
  const int wm = wv & 1, wn = wv >> 1;
  const int m0 = blockIdx.x * 128;
  const int n0 = blockIdx.y * 128;

  const int r0 = tid >> 2;
  const int kg = (tid & 3) ^ (r0 & 3);
  const size_t aoff0 = (size_t)(m0 + r0) * K + kg * 8;
  const size_t aoff1 = (size_t)(m0 + r0 + 64) * K + kg * 8;
  const size_t boff0 = (size_t)(n0 + r0) * K + kg * 8;
  const size_t boff1 = (size_t)(n0 + r0 + 64) * K + kg * 8;
  const int lb0 = wv * 512;
  const int lb1 = 2048 + wv * 512;

  const int l15 = lane & 15, l4 = lane >> 4;
  int afo[4], bfo[4];
#pragma unroll
  for (int mt = 0; mt < 4; ++mt) {
    int r = wm * 64 + mt * 16 + l15;
    afo[mt] = (r * 4 + (l4 ^ (r & 3))) * 8;
  }
#pragma unroll
  for (int nt = 0; nt < 4; ++nt) {
    int r = wn * 64 + nt * 16 + l15;
    bfo[nt] = (r * 4 + (l4 ^ (r & 3))) * 8;
  }

  f32x4 acc[4][4] = {};

  for (int k0 = 0; k0 < K; k0 += 32) {
    __syncthreads();
    gl2lds16(Ah + aoff0 + k0, &sAh[lb0]);
    gl2lds16(Ah + aoff1 + k0, &sAh[lb1]);
    gl2lds16(Al + aoff0 + k0, &sAl[lb0]);
    gl2lds16(Al + aoff1 + k0, &sAl[lb1]);
    gl2lds16(Bh + boff0 + k0, &sBh[lb0]);
    gl2lds16(Bh + boff1 + k0, &sBh[lb1]);
    gl2lds16(Bl + boff0 + k0, &sBl[lb0]);
    gl2lds16(Bl + boff1 + k0, &sBl[lb1]);
    __syncthreads();

    u16x8 a_h[4], a_l[4], b_h[4], b_l[4];
#pragma unroll
    for (int i = 0; i < 4; ++i) {
      a_h[i] = *(const u16x8*)&sAh[afo[i]];
      a_l[i] = *(const u16x8*)&sAl[afo[i]];
      b_h[i] = *(const u16x8*)&sBh[bfo[i]];
      b_l[i] = *(const u16x8*)&sBl[bfo[i]];
    }
#pragma unroll
    for (int mt = 0; mt < 4; ++mt)
#pragma unroll
      for (int nt = 0; nt < 4; ++nt) {
        acc[mt][nt] = mfma16(a_h[mt], b_h[nt], acc[mt][nt]);
        acc[mt][nt] = mfma16(a_l[mt], b_h[nt], acc[mt][nt]);
        acc[mt][nt] = mfma16(a_h[mt], b_l[nt], acc[mt][nt]);
      }
  }

  if (!rec) {
#pragma unroll
    for (int mt = 0; mt < 4; ++mt) {
      int mr = m0 + wm * 64 + mt * 16 + l4 * 4;
#pragma unroll
      for (int nt = 0; nt < 4; ++nt) {
        int nc = n0 + wn * 64 + nt * 16 + l15;
        float bv = bias[nc];
#pragma unroll
        for (int r = 0; r < 4; ++r)
          C[(size_t)(mr + r) * N + nc] = acc[mt][nt][r] + bv;
      }
    }
  } else {
#pragma unroll
    for (int mt = 0; mt < 4; ++mt) {
      int mr = m0 + wm * 64 + mt * 16 + l4 * 4;
      int Bb = mr >> 6, tloc = mr & 63;
      int p = Bb >> 3, bb = Bb & 7;
#pragma unroll
      for (int nt = 0; nt < 4; ++nt) {
        int nc = n0 + wn * 64 + nt * 16 + l15;
        float bv = bias[nc];
        int gate = nc >> 10, unit = nc & 1023;
        int g = unit >> 7, u = unit & 127;
        size_t base = ((size_t)((g * 8 + p) * 64 + tloc)) * 4096 + gate * 1024 + bb * 128 + u;
#pragma unroll
        for (int r = 0; r < 4; ++r)
          C[base + (size_t)r * 4096] = acc[mt][nt][r] + bv;
      }
    }
  }
}

// ---------- l1 pointwise on one chunk ----------
__global__ void k_pw(const float* __restrict__ xg, u16* __restrict__ hhi,
                     u16* __restrict__ hlo) {
  int idx = blockIdx.x * 256 + threadIdx.x;  // MC*H_ threads
  int r = idx >> 10, j = idx & 1023;
  const float* g = xg + (size_t)r * G4;
  float cc = sigmoidf_(g[j]) * tanhf(g[2048 + j]);
  float h = sigmoidf_(g[3072 + j]) * tanhf(cc);
  u16 hh = f2bf(h);
  hhi[idx] = hh;
  hlo[idx] = f2bf(h - bf2f(hh));
}

// ---------- persistent recurrent LSTM, one time-chunk ----------
// 64 blocks x 512 threads. Block = (gate-group g: 128 units, all 4 gates)
// x (batch-part p: 8 batches). blockIdx = p*8+g so all parts of a group land
// on one XCD (round-robin heuristic) -> Whh slice (2 MB) stays L2-resident.
// h (8 batches x 1024 x hi/lo = 32 KB) staged to LDS per step via sc0sc1.
__global__ __launch_bounds__(512, 1) void k_rec(
    const float* __restrict__ xg,                     // rec layout chunk (64 MB)
    const u16* __restrict__ Whi, const u16* __restrict__ Wlo,  // [4096][1024]
    u16* __restrict__ hb_hi, u16* __restrict__ hb_lo, // [2][64][1024] coherent
    float* __restrict__ cb,                           // [64][1024]
    u16* __restrict__ hs_hi, u16* __restrict__ hs_lo, // [MC][1024] or null
    float* __restrict__ hfinal,                       // [64][1024] or null
    u32* __restrict__ flags, int t0)                  // RBLK flags, 64B apart
{
  __shared__ __attribute__((aligned(16))) u16 sH[2 * 8 * 1032];  // 33 KB
  __shared__ float sg[8 * 520];                                  // 16.6 KB

  const int tid = threadIdx.x;
  const int lane = tid & 63, wv = tid >> 6;        // 8 waves
  const int l15 = lane & 15, l4 = lane >> 4;
  const int g = blockIdx.x & 7, p = blockIdx.x >> 3;
  const int u0 = g * 128, b0 = p * 8;

  // B fragment pointers: wave cols c = wv*64 + i*16 + l15; col c -> gate=c>>7, u=c&127
  const u16* bph[4]; const u16* bpl[4];
#pragma unroll
  for (int i = 0; i < 4; ++i) {
    int c = wv * 64 + i * 16 + l15;
    int row = (c >> 7) * 1024 + u0 + (c & 127);
    bph[i] = Whi + (size_t)row * 1024 + l4 * 8;
    bpl[i] = Wlo + (size_t)row * 1024 + l4 * 8;
  }

  // A fragment LDS base: row m = l15 (batches 0..7; 8..15 alias duplicates)
  const int arow = (l15 & 7) * 1032 + l4 * 8;

  // pointwise cells: batch pb, units pu, pu+1
  const int pb = tid >> 6, pu = (tid & 63) * 2;
  const int hoff = (b0 + pb) * 1024 + u0 + pu;
  f32x2 cc = *(const f32x2*)(cb + hoff);

  const float* xgb = xg + ((size_t)(g * 8 + p) * 64) * 4096 + pb * 128 + pu;

  for (int tt = 0; tt < TC; ++tt) {
    const int t = t0 + tt;
    const int rbase = (t & 1) << 16;   // h_{t-1} plane (elements)
    const int wbase = 65536 - rbase;   // h_t plane

    // ---- prefetch this step's xg (issues before the flag wait) ----
    const float* xa = xgb + (size_t)tt * 4096;
    f32x2 px0, px1, px2, px3;
    asm volatile("global_load_dwordx2 %0, %1, off" : "=v"(px0) : "v"(xa));
    asm volatile("global_load_dwordx2 %0, %1, off" : "=v"(px1) : "v"(xa + 1024));
    asm volatile("global_load_dwordx2 %0, %1, off" : "=v"(px2) : "v"(xa + 2048));
    asm volatile("global_load_dwordx2 %0, %1, off" : "=v"(px3) : "v"(xa + 3072));

    // ---- wait for all blocks' h_{t-1} (one flag per lane of wave 0) ----
    if (tt > 0) {
      if (wv == 0) {
        const u32* fp = flags + lane * 16;
        while (__hip_atomic_load(fp, __ATOMIC_RELAXED, __HIP_MEMORY_SCOPE_AGENT) < (u32)tt)
          __builtin_amdgcn_s_sleep(1);
      }
      __syncthreads();
    }

    // ---- stage h_{t-1} (8 batches, hi+lo) into LDS: 4 dwordx4 per thread ----
    {
      u16x8 tmp[4];
#pragma unroll
      for (int i = 0; i < 4; ++i) {
        int j = tid + i * 512;
        int plane = j >> 10, rem = j & 1023;
        int srw = rem >> 7, k16 = rem & 127;
        const u16* sp = (plane ? hb_lo : hb_hi) + rbase + (b0 + srw) * 1024 + k16 * 8;
        tmp[i] = load16_cc(sp);
      }
      waitcnt0();
#pragma unroll
      for (int i = 0; i < 4; ++i) {
        int j = tid + i * 512;
        int plane = j >> 10, rem = j & 1023;
        int srw = rem >> 7, k16 = rem & 127;
        *(u16x8*)&sH[plane * 8256 + srw * 1032 + k16 * 8] = tmp[i];
      }
    }
    __syncthreads();

    // ---- recurrent matmul: gates += h_{t-1} @ Whh^T (split precision) ----
    f32x4 acc[4] = {};
#pragma unroll 4
    for (int kc = 0; kc < 32; ++kc) {
      int ko = kc * 32;
      u16x8 ah = *(const u16x8*)&sH[arow + ko];
      u16x8 al = *(const u16x8*)&sH[8256 + arow + ko];
#pragma unroll
      for (int i = 0; i < 4; ++i) {
        u16x8 bh = *(const u16x8*)(bph[i] + ko);
        u16x8 bl = *(const u16x8*)(bpl[i] + ko);
        acc[i] = mfma16(ah, bh, acc[i]);
        acc[i] = mfma16(al, bh, acc[i]);
        acc[i] = mfma16(ah, bl, acc[i]);
      }
    }

    // ---- gather valid gate partials (rows m<8) to LDS ----
    if (l4 < 2) {
#pragma unroll
      for (int r = 0; r < 4; ++r) {
        int m = l4 * 4 + r;
#pragma unroll
        for (int i = 0; i < 4; ++i)
          sg[m * 520 + wv * 64 + i * 16 + l15] = acc[i][r];
      }
    }
    __syncthreads();

    // ---- pointwise: 2 adjacent-unit cells per thread ----
    {
      waitcnt0();  // px ready (drained with staging wait or here)
      const float* sr = sg + pb * 520;
      float gi0 = sr[pu] + px0[0],        gi1 = sr[pu + 1] + px0[1];
      float gf0 = sr[128 + pu] + px1[0],  gf1 = sr[128 + pu + 1] + px1[1];
      float gg0 = sr[256 + pu] + px2[0],  gg1 = sr[256 + pu + 1] + px2[1];
      float go0 = sr[384 + pu] + px3[0],  go1 = sr[384 + pu + 1] + px3[1];
      float c0 = sigmoidf_(gf0) * cc[0] + sigmoidf_(gi0) * tanhf(gg0);
      float c1 = sigmoidf_(gf1) * cc[1] + sigmoidf_(gi1) * tanhf(gg1);
      float h0 = sigmoidf_(go0) * tanhf(c0);
      float h1 = sigmoidf_(go1) * tanhf(c1);
      cc[0] = c0; cc[1] = c1;
      u16 h0h = f2bf(h0), h1h = f2bf(h1);
      u32 hiPair = (u32)h0h | ((u32)h1h << 16);
      u32 loPair = (u32)f2bf(h0 - bf2f(h0h)) | ((u32)f2bf(h1 - bf2f(h1h)) << 16);
      store4_cc(hb_hi + wbase + hoff, hiPair);
      store4_cc(hb_lo + wbase + hoff, loPair);
      if (hs_hi) {
        size_t so = ((size_t)(b0 + pb) * TC + tt) * 1024 + u0 + pu;
        *(u32*)(hs_hi + so) = hiPair;
        *(u32*)(hs_lo + so) = loPair;
      }
      if (hfinal && t == T_ - 1) {
        f32x2 hv = {h0, h1};
        *(f32x2*)(hfinal + hoff) = hv;
      }
    }

    // ---- release: drain h stores, then raise own flag ----
    waitcnt0();
    __syncthreads();
    if (tid == 0)
      __hip_atomic_store(flags + blockIdx.x * 16, (u32)(tt + 1),
                         __ATOMIC_RELEASE, __HIP_MEMORY_SCOPE_AGENT);
  }

  *(f32x2*)(cb + hoff) = cc;
}

// ---------- MLP (fp32 vector) ----------
__global__ void k_fc(const float* __restrict__ in, const float* __restrict__ W,
                     const float* __restrict__ bias, float* __restrict__ out,
                     int K, int N, int relu) {
  int b = blockIdx.x;
  int n = blockIdx.y * 256 + threadIdx.x;
  if (n >= N) return;
  const float4* wr = (const float4*)(W + (size_t)n * K);
  const float4* xr = (const float4*)(in + (size_t)b * K);
  float s = 0.f;
  for (int k = 0; k < K / 4; ++k) {
    float4 w = wr[k], x = xr[k];
    s += w.x * x.x + w.y * x.y + w.z * x.z + w.w * x.w;
  }
  s += bias[n];
  if (relu) s = fmaxf(s, 0.f);
  out[(size_t)b * N + n] = s;
}

__global__ void k_out(const float* __restrict__ z, const float* __restrict__ W3,
                      const float* __restrict__ b3, float* __restrict__ outp) {
  int b = blockIdx.x;
  int lane = threadIdx.x;  // 64
  const float4* wr = (const float4*)W3;
  const float4* xr = (const float4*)(z + b * 512);
  float s = 0.f;
  for (int k = lane; k < 128; k += 64) {
    float4 w = wr[k], x = xr[k];
    s += w.x * x.x + w.y * x.y + w.z * x.z + w.w * x.w;
  }
  for (int off = 32; off; off >>= 1) s += __shfl_down(s, off);
  if (lane == 0) outp[b] = s + b3[0];
}

// ---------- launch ----------
extern "C" void kernel_launch(void* const* d_in, const int* in_sizes, int n_in,
                              void* d_out, int out_size, void* d_ws, size_t ws_size,
                              hipStream_t stream) {
  (void)in_sizes; (void)n_in; (void)out_size; (void)ws_size;
  const float* xx  = (const float*)d_in[0];
  const float* W10 = (const float*)d_in[1];
  const float* b10i = (const float*)d_in[2];
  const float* b10h = (const float*)d_in[3];
  const float* W11 = (const float*)d_in[4];
  const float* b11i = (const float*)d_in[5];
  const float* b11h = (const float*)d_in[6];
  const float* W20 = (const float*)d_in[7];
  const float* Wh0 = (const float*)d_in[8];
  const float* b20i = (const float*)d_in[9];
  const float* b20h = (const float*)d_in[10];
  const float* W21 = (const float*)d_in[11];
  const float* Wh1 = (const float*)d_in[12];
  const float* b21i = (const float*)d_in[13];
  const float* b21h = (const float*)d_in[14];
  const float* mW1 = (const float*)d_in[15];
  const float* mb1 = (const float*)d_in[16];
  const float* mW2 = (const float*)d_in[17];
  const float* mb2 = (const float*)d_in[18];
  const float* mW3 = (const float*)d_in[19];
  const float* mb3 = (const float*)d_in[20];

  char* ws = (char*)d_ws;
  size_t o = 0;
  float* XG = (float*)(ws + o); o += (size_t)MC * G4 * 4;            // 64 MiB
  u16* Aah = (u16*)(ws + o); o += (size_t)MC * H_ * 2;               // ACT ping
  u16* Aal = (u16*)(ws + o); o += (size_t)MC * H_ * 2;
  u16* Abh = (u16*)(ws + o); o += (size_t)MC * H_ * 2;               // ACT pong
  u16* Abl = (u16*)(ws + o); o += (size_t)MC * H_ * 2;
  u16* XXh = (u16*)(ws + o); o += (size_t)MC * D_ * 2;
  u16* XXl = (u16*)(ws + o); o += (size_t)MC * D_ * 2;
  u16* W10h = (u16*)(ws + o); o += (size_t)G4 * D_ * 2;
  u16* W10l = (u16*)(ws + o); o += (size_t)G4 * D_ * 2;
  u16* W11h = (u16*)(ws + o); o += (size_t)G4 * H_ * 2;
  u16* W11l = (u16*)(ws + o); o += (size_t)G4 * H_ * 2;
  u16* W20h = (u16*)(ws + o); o += (size_t)G4 * H_ * 2;
  u16* W20l = (u16*)(ws + o); o += (size_t)G4 * H_ * 2;
  u16* Wh0h = (u16*)(ws + o); o += (size_t)G4 * H_ * 2;
  u16* Wh0l = (u16*)(ws + o); o += (size_t)G4 * H_ * 2;
  u16* W21h = (u16*)(ws + o); o += (size_t)G4 * H_ * 2;
  u16* W21l = (u16*)(ws + o); o += (size_t)G4 * H_ * 2;
  u16* Wh1h = (u16*)(ws + o); o += (size_t)G4 * H_ * 2;
  u16* Wh1l = (u16*)(ws + o); o += (size_t)G4 * H_ * 2;
  float* bs0 = (float*)(ws + o); o += G4 * 4;
  float* bs1 = (float*)(ws + o); o += G4 * 4;
  float* bs2 = (float*)(ws + o); o += G4 * 4;
  float* bs3 = (float*)(ws + o); o += G4 * 4;
  // state region (zeroed once per launch, contiguous)
  char* ST = ws + o;
  u16* hb0h = (u16*)(ws + o); o += 2 * B_ * H_ * 2;
  u16* hb0l = (u16*)(ws + o); o += 2 * B_ * H_ * 2;
  u16* hb1h = (u16*)(ws + o); o += 2 * B_ * H_ * 2;
  u16* hb1l = (u16*)(ws + o); o += 2 * B_ * H_ * 2;
  float* cb0 = (float*)(ws + o); o += B_ * H_ * 4;
  float* cb1 = (float*)(ws + o); o += B_ * H_ * 4;
  u32* FLG = (u32*)(ws + o); o += 8 * RBLK * 16 * 4;   // 8 instances x 64 flags x 64B
  size_t stBytes = (size_t)((ws + o) - ST);
  float* FH = (float*)(ws + o); o += B_ * H_ * 4;
  float* Z1 = (float*)(ws + o); o += B_ * H_ * 4;
  float* Z2 = (float*)(ws + o); o += B_ * 512 * 4;

  // --- one-time weight/bias prep ---
  k_split<<<(G4 * D_ / 4 + 255) / 256, 256, 0, stream>>>(W10, W10h, W10l, G4 * D_ / 4);
  k_split<<<(G4 * H_ / 4 + 255) / 256, 256, 0, stream>>>(W11, W11h, W11l, G4 * H_ / 4);
  k_split<<<(G4 * H_ / 4 + 255) / 256, 256, 0, stream>>>(W20, W20h, W20l, G4 * H_ / 4);
  k_split<<<(G4 * H_ / 4 + 255) / 256, 256, 0, stream>>>(Wh0, Wh0h, Wh0l, G4 * H_ / 4);
  k_split<<<(G4 * H_ / 4 + 255) / 256, 256, 0, stream>>>(W21, W21h, W21l, G4 * H_ / 4);
  k_split<<<(G4 * H_ / 4 + 255) / 256, 256, 0, stream>>>(Wh1, Wh1h, Wh1l, G4 * H_ / 4);
  k_addvec<<<16, 256, 0, stream>>>(b10i, b10h, bs0, G4);
  k_addvec<<<16, 256, 0, stream>>>(b11i, b11h, bs1, G4);
  k_addvec<<<16, 256, 0, stream>>>(b20i, b20h, bs2, G4);
  k_addvec<<<16, 256, 0, stream>>>(b21i, b21h, bs3, G4);
  hipMemsetAsync(ST, 0, stBytes, stream);

  dim3 gg(MC / 128, G4 / 128);
  const int pwBlocks = MC * H_ / 256;

  for (int c = 0; c < NCHUNK; ++c) {
    int t0 = c * TC;
    k_split_x<<<(MC * (D_ / 4) + 255) / 256, 256, 0, stream>>>(xx, XXh, XXl, t0);
    // l1 layer 0
    k_gemm3<<<gg, 256, 0, stream>>>(XXh, XXl, W10h, W10l, bs0, XG, MC, G4, D_, 0);
    k_pw<<<pwBlocks, 256, 0, stream>>>(XG, Aah, Aal);
    // l1 layer 1
    k_gemm3<<<gg, 256, 0, stream>>>(Aah, Aal, W11h, W11l, bs1, XG, MC, G4, H_, 0);
    k_pw<<<pwBlocks, 256, 0, stream>>>(XG, Abh, Abl);
    // l2 layer 0 (rec-layout gates)
    k_gemm3<<<gg, 256, 0, stream>>>(Abh, Abl, W20h, W20l, bs2, XG, MC, G4, H_, 1);
    k_rec<<<RBLK, 512, 0, stream>>>(XG, Wh0h, Wh0l, hb0h, hb0l, cb0,
                                    Aah, Aal, nullptr, FLG + (c * 2) * RBLK * 16, t0);
    // l2 layer 1 (rec-layout gates)
    k_gemm3<<<gg, 256, 0, stream>>>(Aah, Aal, W21h, W21l, bs3, XG, MC, G4, H_, 1);
    k_rec<<<RBLK, 512, 0, stream>>>(XG, Wh1h, Wh1l, hb1h, hb1l, cb1,
                                    nullptr, nullptr, FH, FLG + (c * 2 + 1) * RBLK * 16, t0);
  }

  // MLP
  k_fc<<<dim3(B_, 4), 256, 0, stream>>>(FH, mW1, mb1, Z1, H_, H_, 1);
  k_fc<<<dim3(B_, 2), 256, 0, stream>>>(Z1, mW2, mb2, Z2, H_, 512, 1);
  k_out<<<B_, 64, 0, stream>>>(Z2, mW3, mb3, (float*)d_out);
}

// Round 6
// 6770.618 us; speedup vs baseline: 4.7499x; 4.7499x over previous
//
#include <hip/hip_runtime.h>

typedef unsigned short u16;
typedef unsigned int u32;
typedef u16 u16x8 __attribute__((ext_vector_type(8)));
typedef u16 u16x4 __attribute__((ext_vector_type(4)));
typedef __bf16 bf16x8 __attribute__((ext_vector_type(8)));
typedef float f32x4 __attribute__((ext_vector_type(4)));
typedef float f32x2 __attribute__((ext_vector_type(2)));

#define B_ 64
#define T_ 256
#define D_ 256
#define H_ 1024
#define G4 4096
#define TC 64            // timesteps per chunk
#define MC 4096          // rows per chunk (B_*TC)
#define NCHUNK 4
#define RBLK 256         // k_rec blocks: 128 unit-groups x 2 batch-halves

// ---------- helpers ----------
__device__ __forceinline__ u16 f2bf(float x) {
  u32 u = __builtin_bit_cast(u32, x);
  u += 0x7fffu + ((u >> 16) & 1u);
  return (u16)(u >> 16);
}
__device__ __forceinline__ float bf2f(u16 h) {
  u32 u = ((u32)h) << 16;
  return __builtin_bit_cast(float, u);
}
__device__ __forceinline__ float sigmoidf_(float x) { return 1.f / (1.f + __expf(-x)); }

__device__ __forceinline__ f32x4 mfma16(u16x8 a, u16x8 b, f32x4 c) {
  return __builtin_amdgcn_mfma_f32_16x16x32_bf16(
      __builtin_bit_cast(bf16x8, a), __builtin_bit_cast(bf16x8, b), c, 0, 0, 0);
}

__device__ __forceinline__ void gl2lds16(const u16* g, u16* l) {
  __builtin_amdgcn_global_load_lds(
      (const __attribute__((address_space(1))) u32*)(const void*)g,
      (__attribute__((address_space(3))) u32*)(void*)l, 16, 0, 0);
}

// device-coherent (write-through past non-coherent L2) 4B store
__device__ __forceinline__ void store4_cc(u16* p, u32 v) {
  asm volatile("global_store_dword %0, %1, off sc0 sc1" :: "v"(p), "v"(v) : "memory");
}
__device__ __forceinline__ void waitcnt0() {
  asm volatile("s_waitcnt vmcnt(0)" ::: "memory");
}

// ---------- split fp32 -> (hi, lo) bf16 planes ----------
__global__ void k_split(const float* __restrict__ src, u16* __restrict__ hi,
                        u16* __restrict__ lo, int n4) {
  int i = blockIdx.x * 256 + threadIdx.x;
  if (i >= n4) return;
  const float4* s4 = (const float4*)src;
  float4 v = s4[i];
  u16 h0 = f2bf(v.x), h1 = f2bf(v.y), h2 = f2bf(v.z), h3 = f2bf(v.w);
  u16x4 hv = {h0, h1, h2, h3};
  u16x4 lv = {f2bf(v.x - bf2f(h0)), f2bf(v.y - bf2f(h1)),
              f2bf(v.z - bf2f(h2)), f2bf(v.w - bf2f(h3))};
  *(u16x4*)(hi + 4 * (size_t)i) = hv;
  *(u16x4*)(lo + 4 * (size_t)i) = lv;
}

// gather one time-chunk of xx ([B,T,D] -> [B*TC, D]) and split planes
__global__ void k_split_x(const float* __restrict__ xx, u16* __restrict__ hi,
                          u16* __restrict__ lo, int t0) {
  int i = blockIdx.x * 256 + threadIdx.x;   // over MC * D_/4
  if (i >= MC * (D_ / 4)) return;
  int row = i >> 6, c4 = i & 63;
  int b = row >> 6, tc = row & 63;
  const float4* s4 = (const float4*)xx;
  float4 v = s4[(size_t)(b * T_ + t0 + tc) * (D_ / 4) + c4];
  u16 h0 = f2bf(v.x), h1 = f2bf(v.y), h2 = f2bf(v.z), h3 = f2bf(v.w);
  u16x4 hv = {h0, h1, h2, h3};
  u16x4 lv = {f2bf(v.x - bf2f(h0)), f2bf(v.y - bf2f(h1)),
              f2bf(v.z - bf2f(h2)), f2bf(v.w - bf2f(h3))};
  *(u16x4*)(hi + 4 * (size_t)i) = hv;
  *(u16x4*)(lo + 4 * (size_t)i) = lv;
}

__global__ void k_addvec(const float* __restrict__ a, const float* __restrict__ b,
                         float* __restrict__ o, int n) {
  int i = blockIdx.x * 256 + threadIdx.x;
  if (i < n) o[i] = a[i] + b[i];
}

// ---------- split-precision GEMM: C[M,N] = A[M,K] * B[N,K]^T + bias (fp32 out) ----
// rec=0: standard C[m][n].
// rec=1/2: k_rec xg layout idx = (((ublk*2+ph)*64 + tloc)*32 + bb)*32 + col
//   with unit=n&1023, ublk=unit>>3, col=(n>>10)*8+(unit&7); B=ph*32+bb.
//   rec=1: A rows b-major (B=m>>6, tloc=m&63); rec=2: t-major (B=m&63, tloc=m>>6).
__global__ __launch_bounds__(256, 2) void k_gemm3(
    const u16* __restrict__ Ah, const u16* __restrict__ Al,
    const u16* __restrict__ Bh, const u16* __restrict__ Bl,
    const float* __restrict__ bias, float* __restrict__ C,
    int M, int N, int K, int rec)
{
  __shared__ __attribute__((aligned(16))) u16 sAh[4096];
  __shared__ __attribute__((aligned(16))) u16 sAl[4096];
  __shared__ __attribute__((aligned(16))) u16 sBh[4096];
  __shared__ __attribute__((aligned(16))) u16 sBl[4096];

  const int tid = threadIdx.x;
  const int lane = tid & 63;
  const int wv = tid >> 6;
  const int wm = wv & 1, wn = wv >> 1;
  const int m0 = blockIdx.x * 128;
  const int n0 = blockIdx.y * 128;

  const int r0 = tid >> 2;
  const int kg = (tid & 3) ^ (r0 & 3);
  const size_t aoff0 = (size_t)(m0 + r0) * K + kg * 8;
  const size_t aoff1 = (size_t)(m0 + r0 + 64) * K + kg * 8;
  const size_t boff0 = (size_t)(n0 + r0) * K + kg * 8;
  const size_t boff1 = (size_t)(n0 + r0 + 64) * K + kg * 8;
  const int lb0 = wv * 512;
  const int lb1 = 2048 + wv * 512;

  const int l15 = lane & 15, l4 = lane >> 4;
  int afo[4], bfo[4];
#pragma unroll
  for (int mt = 0; mt < 4; ++mt) {
    int r = wm * 64 + mt * 16 + l15;
    afo[mt] = (r * 4 + (l4 ^ (r & 3))) * 8;
  }
#pragma unroll
  for (int nt = 0; nt < 4; ++nt) {
    int r = wn * 64 + nt * 16 + l15;
    bfo[nt] = (r * 4 + (l4 ^ (r & 3))) * 8;
  }

  f32x4 acc[4][4] = {};

  for (int k0 = 0; k0 < K; k0 += 32) {
    __syncthreads();
    gl2lds16(Ah + aoff0 + k0, &sAh[lb0]);
    gl2lds16(Ah + aoff1 + k0, &sAh[lb1]);
    gl2lds16(Al + aoff0 + k0, &sAl[lb0]);
    gl2lds16(Al + aoff1 + k0, &sAl[lb1]);
    gl2lds16(Bh + boff0 + k0, &sBh[lb0]);
    gl2lds16(Bh + boff1 + k0, &sBh[lb1]);
    gl2lds16(Bl + boff0 + k0, &sBl[lb0]);
    gl2lds16(Bl + boff1 + k0, &sBl[lb1]);
    __syncthreads();

    u16x8 a_h[4], a_l[4], b_h[4], b_l[4];
#pragma unroll
    for (int i = 0; i < 4; ++i) {
      a_h[i] = *(const u16x8*)&sAh[afo[i]];
      a_l[i] = *(const u16x8*)&sAl[afo[i]];
      b_h[i] = *(const u16x8*)&sBh[bfo[i]];
      b_l[i] = *(const u16x8*)&sBl[bfo[i]];
    }
#pragma unroll
    for (int mt = 0; mt < 4; ++mt)
#pragma unroll
      for (int nt = 0; nt < 4; ++nt) {
        acc[mt][nt] = mfma16(a_h[mt], b_h[nt], acc[mt][nt]);
        acc[mt][nt] = mfma16(a_l[mt], b_h[nt], acc[mt][nt]);
        acc[mt][nt] = mfma16(a_h[mt], b_l[nt], acc[mt][nt]);
      }
  }

  if (!rec) {
#pragma unroll
    for (int mt = 0; mt < 4; ++mt) {
      int mr = m0 + wm * 64 + mt * 16 + l4 * 4;
#pragma unroll
      for (int nt = 0; nt < 4; ++nt) {
        int nc = n0 + wn * 64 + nt * 16 + l15;
        float bv = bias[nc];
#pragma unroll
        for (int r = 0; r < 4; ++r)
          C[(size_t)(mr + r) * N + nc] = acc[mt][nt][r] + bv;
      }
    }
  } else {
#pragma unroll
    for (int mt = 0; mt < 4; ++mt) {
      int mr = m0 + wm * 64 + mt * 16 + l4 * 4;
#pragma unroll
      for (int nt = 0; nt < 4; ++nt) {
        int nc = n0 + wn * 64 + nt * 16 + l15;
        float bv = bias[nc];
        int unit = nc & 1023;
        int ublk = unit >> 3;
        int col = (nc >> 10) * 8 + (unit & 7);
#pragma unroll
        for (int r = 0; r < 4; ++r) {
          int m = mr + r;
          int Bb = (rec == 1) ? (m >> 6) : (m & 63);
          int tloc = (rec == 1) ? (m & 63) : (m >> 6);
          size_t idx = ((size_t)((ublk * 2 + (Bb >> 5)) * 64 + tloc) * 32 + (Bb & 31)) * 32 + col;
          C[idx] = acc[mt][nt][r] + bv;
        }
      }
    }
  }
}

// ---------- l1 pointwise on one chunk ----------
__global__ void k_pw(const float* __restrict__ xg, u16* __restrict__ hhi,
                     u16* __restrict__ hlo) {
  int idx = blockIdx.x * 256 + threadIdx.x;  // MC*H_ threads
  int r = idx >> 10, j = idx & 1023;
  const float* g = xg + (size_t)r * G4;
  float cc = sigmoidf_(g[j]) * tanhf(g[2048 + j]);
  float h = sigmoidf_(g[3072 + j]) * tanhf(cc);
  u16 hh = f2bf(h);
  hhi[idx] = hh;
  hlo[idx] = f2bf(h - bf2f(hh));
}

// ---------- persistent recurrent LSTM, one time-chunk ----------
// 256 blocks x 512 threads, 1 block/CU (150KB LDS). Block = (unit-group: 8 units,
// all 4 gates -> 32 gate-cols, Whh hi+lo slice RESIDENT IN LDS) x (32-batch half).
// h exchange: sc0sc1 write-through stores to a 64-slot ring (aliases Ab / next
// GEMM's A); consumers use NORMAL cached loads on the (cold) slot -> L2-served.
__global__ __launch_bounds__(512, 2) void k_rec(
    const float* __restrict__ xg,                     // rec layout chunk (64 MB)
    const u16* __restrict__ Whi, const u16* __restrict__ Wlo,  // [4096][1024]
    u16* __restrict__ ringH, u16* __restrict__ ringL, // [64][64][1024] bf16 planes
    u16* __restrict__ h0H, u16* __restrict__ h0L,     // [64][1024] chunk-carry h
    float* __restrict__ cb,                           // [64][1024] c state
    float* __restrict__ hfinal,                       // [64][1024] or null
    u32* __restrict__ flags, int t0)                  // RBLK flags, 64B apart
{
  __shared__ __attribute__((aligned(16))) u16 sW[66048];  // [2][32][1032]  129 KB
  __shared__ float sg[4][32][36];                          // [kh][m][col]   18 KB

  const int tid = threadIdx.x;
  const int lane = tid & 63, wv = tid >> 6;
  const int l15 = lane & 15, l4 = lane >> 4;
  const int blk = blockIdx.x;
  const int ublk = blk >> 1, ph = blk & 1;
  const int u0 = ublk * 8, bb0 = ph * 32;

  // ---- one-time: Whh slice (32 gate-cols x 1024, hi+lo) into LDS ----
  for (int ci = tid; ci < 8192; ci += 512) {
    int plane = ci >> 12, rem = ci & 4095;
    int n = rem >> 7, ch = rem & 127;
    int wrow = (n >> 3) * 1024 + u0 + (n & 7);
    const u16* src = (plane ? Wlo : Whi) + (size_t)wrow * 1024 + ch * 8;
    *(u16x8*)&sW[plane * 33024 + n * 1032 + ch * 8] = *(const u16x8*)src;
  }
  __syncthreads();

  const int mt = wv & 1, kh = wv >> 1;        // m-tile(16 batches), k-quarter(8 kc)
  const int am = bb0 + mt * 16 + l15;         // global batch row for A
  const int aoff = am * 1024 + l4 * 8;
  const int bof0 = l15 * 1032 + l4 * 8;
  const int bof1 = (16 + l15) * 1032 + l4 * 8;

  // pointwise cell (tid<256): local batch pb (0..31), unit uu (0..7)
  const int pb = tid >> 3, uu = tid & 7;
  const int cidx = (bb0 + pb) * 1024 + u0 + uu;
  float c = 0.f;
  if (tid < 256) c = cb[cidx];
  const float* xgb = xg + (size_t)blk * 65536 + pb * 32 + uu;

  for (int tt = 0; tt < TC; ++tt) {
    // ---- xg prefetch (produced by an earlier dispatch; safe pre-barrier) ----
    float px0, px1, px2, px3;
    if (tid < 256) {
      const float* xa = xgb + (size_t)tt * 1024;
      asm volatile("global_load_dword %0, %1, off" : "=v"(px0) : "v"(xa));
      asm volatile("global_load_dword %0, %1, off" : "=v"(px1) : "v"(xa + 8));
      asm volatile("global_load_dword %0, %1, off" : "=v"(px2) : "v"(xa + 16));
      asm volatile("global_load_dword %0, %1, off" : "=v"(px3) : "v"(xa + 24));
    }

    // ---- wait for all blocks' h_{t-1} (4 flags per lane of wave 0) ----
    if (tt > 0) {
      if (wv == 0) {
        const u32* fp = flags + lane * 16;
        for (;;) {
          u32 a0 = __hip_atomic_load(fp,        __ATOMIC_RELAXED, __HIP_MEMORY_SCOPE_AGENT);
          u32 a1 = __hip_atomic_load(fp + 1024, __ATOMIC_RELAXED, __HIP_MEMORY_SCOPE_AGENT);
          u32 a2 = __hip_atomic_load(fp + 2048, __ATOMIC_RELAXED, __HIP_MEMORY_SCOPE_AGENT);
          u32 a3 = __hip_atomic_load(fp + 3072, __ATOMIC_RELAXED, __HIP_MEMORY_SCOPE_AGENT);
          if (a0 >= (u32)tt && a1 >= (u32)tt && a2 >= (u32)tt && a3 >= (u32)tt) break;
          __builtin_amdgcn_s_sleep(1);
        }
      }
      __syncthreads();
    }

    // ---- recurrent matmul over this wave's k-quarter (A: normal cached loads) --
    const u16* pAh = tt ? ringH + (size_t)(tt - 1) * 65536 : h0H;
    const u16* pAl = tt ? ringL + (size_t)(tt - 1) * 65536 : h0L;
    f32x4 acc0 = {}, acc1 = {};
#pragma unroll
    for (int kc = 0; kc < 8; ++kc) {
      int k = kh * 256 + kc * 32;
      u16x8 ah = *(const u16x8*)(pAh + aoff + k);
      u16x8 al = *(const u16x8*)(pAl + aoff + k);
      u16x8 bh0 = *(const u16x8*)&sW[bof0 + k];
      u16x8 bl0 = *(const u16x8*)&sW[33024 + bof0 + k];
      u16x8 bh1 = *(const u16x8*)&sW[bof1 + k];
      u16x8 bl1 = *(const u16x8*)&sW[33024 + bof1 + k];
      acc0 = mfma16(ah, bh0, acc0);
      acc0 = mfma16(al, bh0, acc0);
      acc0 = mfma16(ah, bl0, acc0);
      acc1 = mfma16(ah, bh1, acc1);
      acc1 = mfma16(al, bh1, acc1);
      acc1 = mfma16(ah, bl1, acc1);
    }

    // ---- gather k-partial gate sums (C layout col=l15, row=l4*4+r) ----
#pragma unroll
    for (int r = 0; r < 4; ++r) {
      int m = mt * 16 + l4 * 4 + r;
      sg[kh][m][l15] = acc0[r];
      sg[kh][m][16 + l15] = acc1[r];
    }
    __syncthreads();

    // ---- pointwise on 256 threads; pack h pairs; sc0sc1 ring store ----
    if (tid < 256) {
      waitcnt0();  // px ready
      float gi = sg[0][pb][uu]      + sg[1][pb][uu]      + sg[2][pb][uu]      + sg[3][pb][uu]      + px0;
      float gf = sg[0][pb][8 + uu]  + sg[1][pb][8 + uu]  + sg[2][pb][8 + uu]  + sg[3][pb][8 + uu]  + px1;
      float gg = sg[0][pb][16 + uu] + sg[1][pb][16 + uu] + sg[2][pb][16 + uu] + sg[3][pb][16 + uu] + px2;
      float go = sg[0][pb][24 + uu] + sg[1][pb][24 + uu] + sg[2][pb][24 + uu] + sg[3][pb][24 + uu] + px3;
      c = sigmoidf_(gf) * c + sigmoidf_(gi) * tanhf(gg);
      float h = sigmoidf_(go) * tanhf(c);
      u32 hiu = (u32)f2bf(h);
      u32 lou = (u32)f2bf(h - bf2f((u16)hiu));
      u32 hiN = __shfl_down(hiu, 1);
      u32 loN = __shfl_down(lou, 1);
      if ((tid & 1) == 0) {
        size_t re = (size_t)(tt * 64 + bb0 + pb) * 1024 + u0 + uu;
        store4_cc(ringH + re, hiu | (hiN << 16));
        store4_cc(ringL + re, lou | (loN << 16));
        if (tt == TC - 1) {
          store4_cc(h0H + cidx, hiu | (hiN << 16));
          store4_cc(h0L + cidx, lou | (loN << 16));
        }
      }
      if (hfinal && t0 + tt == T_ - 1) hfinal[cidx] = h;
    }

    // ---- release: drain stores (all waves), then raise own flag ----
    waitcnt0();
    __syncthreads();
    if (tid == 0)
      __hip_atomic_store(flags + blk * 16, (u32)(tt + 1),
                         __ATOMIC_RELEASE, __HIP_MEMORY_SCOPE_AGENT);
  }

  if (tid < 256) cb[cidx] = c;
}

// ---------- MLP (fp32 vector) ----------
__global__ void k_fc(const float* __restrict__ in, const float* __restrict__ W,
                     const float* __restrict__ bias, float* __restrict__ out,
                     int K, int N, int relu) {
  int b = blockIdx.x;
  int n = blockIdx.y * 256 + threadIdx.x;
  if (n >= N) return;
  const float4* wr = (const float4*)(W + (size_t)n * K);
  const float4* xr = (const float4*)(in + (size_t)b * K);
  float s = 0.f;
  for (int k = 0; k < K / 4; ++k) {
    float4 w = wr[k], x = xr[k];
    s += w.x * x.x + w.y * x.y + w.z * x.z + w.w * x.w;
  }
  s += bias[n];
  if (relu) s = fmaxf(s, 0.f);
  out[(size_t)b * N + n] = s;
}

__global__ void k_out(const float* __restrict__ z, const float* __restrict__ W3,
                      const float* __restrict__ b3, float* __restrict__ outp) {
  int b = blockIdx.x;
  int lane = threadIdx.x;  // 64
  const float4* wr = (const float4*)W3;
  const float4* xr = (const float4*)(z + b * 512);
  float s = 0.f;
  for (int k = lane; k < 128; k += 64) {
    float4 w = wr[k], x = xr[k];
    s += w.x * x.x + w.y * x.y + w.z * x.z + w.w * x.w;
  }
  for (int off = 32; off; off >>= 1) s += __shfl_down(s, off);
  if (lane == 0) outp[b] = s + b3[0];
}

// ---------- launch ----------
extern "C" void kernel_launch(void* const* d_in, const int* in_sizes, int n_in,
                              void* d_out, int out_size, void* d_ws, size_t ws_size,
                              hipStream_t stream) {
  (void)in_sizes; (void)n_in; (void)out_size; (void)ws_size;
  const float* xx  = (const float*)d_in[0];
  const float* W10 = (const float*)d_in[1];
  const float* b10i = (const float*)d_in[2];
  const float* b10h = (const float*)d_in[3];
  const float* W11 = (const float*)d_in[4];
  const float* b11i = (const float*)d_in[5];
  const float* b11h = (const float*)d_in[6];
  const float* W20 = (const float*)d_in[7];
  const float* Wh0 = (const float*)d_in[8];
  const float* b20i = (const float*)d_in[9];
  const float* b20h = (const float*)d_in[10];
  const float* W21 = (const float*)d_in[11];
  const float* Wh1 = (const float*)d_in[12];
  const float* b21i = (const float*)d_in[13];
  const float* b21h = (const float*)d_in[14];
  const float* mW1 = (const float*)d_in[15];
  const float* mb1 = (const float*)d_in[16];
  const float* mW2 = (const float*)d_in[17];
  const float* mb2 = (const float*)d_in[18];
  const float* mW3 = (const float*)d_in[19];
  const float* mb3 = (const float*)d_in[20];

  char* ws = (char*)d_ws;
  size_t o = 0;
  float* XG = (float*)(ws + o); o += (size_t)MC * G4 * 4;            // 64 MiB
  u16* Aah = (u16*)(ws + o); o += (size_t)MC * H_ * 2;               // l1 ping
  u16* Aal = (u16*)(ws + o); o += (size_t)MC * H_ * 2;
  u16* Abh = (u16*)(ws + o); o += (size_t)MC * H_ * 2;               // l1 pong / h ring
  u16* Abl = (u16*)(ws + o); o += (size_t)MC * H_ * 2;
  u16* XXh = (u16*)(ws + o); o += (size_t)MC * D_ * 2;
  u16* XXl = (u16*)(ws + o); o += (size_t)MC * D_ * 2;
  u16* W10h = (u16*)(ws + o); o += (size_t)G4 * D_ * 2;
  u16* W10l = (u16*)(ws + o); o += (size_t)G4 * D_ * 2;
  u16* W11h = (u16*)(ws + o); o += (size_t)G4 * H_ * 2;
  u16* W11l = (u16*)(ws + o); o += (size_t)G4 * H_ * 2;
  u16* W20h = (u16*)(ws + o); o += (size_t)G4 * H_ * 2;
  u16* W20l = (u16*)(ws + o); o += (size_t)G4 * H_ * 2;
  u16* Wh0h = (u16*)(ws + o); o += (size_t)G4 * H_ * 2;
  u16* Wh0l = (u16*)(ws + o); o += (size_t)G4 * H_ * 2;
  u16* W21h = (u16*)(ws + o); o += (size_t)G4 * H_ * 2;
  u16* W21l = (u16*)(ws + o); o += (size_t)G4 * H_ * 2;
  u16* Wh1h = (u16*)(ws + o); o += (size_t)G4 * H_ * 2;
  u16* Wh1l = (u16*)(ws + o); o += (size_t)G4 * H_ * 2;
  float* bs0 = (float*)(ws + o); o += G4 * 4;
  float* bs1 = (float*)(ws + o); o += G4 * 4;
  float* bs2 = (float*)(ws + o); o += G4 * 4;
  float* bs3 = (float*)(ws + o); o += G4 * 4;
  // state region (zeroed once per launch, contiguous)
  char* ST = ws + o;
  u16* h00H = (u16*)(ws + o); o += B_ * H_ * 2;
  u16* h00L = (u16*)(ws + o); o += B_ * H_ * 2;
  u16* h01H = (u16*)(ws + o); o += B_ * H_ * 2;
  u16* h01L = (u16*)(ws + o); o += B_ * H_ * 2;
  float* cb0 = (float*)(ws + o); o += B_ * H_ * 4;
  float* cb1 = (float*)(ws + o); o += B_ * H_ * 4;
  u32* FLG = (u32*)(ws + o); o += 8 * RBLK * 16 * 4;   // 8 instances x 256 flags x 64B
  size_t stBytes = (size_t)((ws + o) - ST);
  float* FH = (float*)(ws + o); o += B_ * H_ * 4;
  float* Z1 = (float*)(ws + o); o += B_ * H_ * 4;
  float* Z2 = (float*)(ws + o); o += B_ * 512 * 4;

  // --- one-time weight/bias prep ---
  k_split<<<(G4 * D_ / 4 + 255) / 256, 256, 0, stream>>>(W10, W10h, W10l, G4 * D_ / 4);
  k_split<<<(G4 * H_ / 4 + 255) / 256, 256, 0, stream>>>(W11, W11h, W11l, G4 * H_ / 4);
  k_split<<<(G4 * H_ / 4 + 255) / 256, 256, 0, stream>>>(W20, W20h, W20l, G4 * H_ / 4);
  k_split<<<(G4 * H_ / 4 + 255) / 256, 256, 0, stream>>>(Wh0, Wh0h, Wh0l, G4 * H_ / 4);
  k_split<<<(G4 * H_ / 4 + 255) / 256, 256, 0, stream>>>(W21, W21h, W21l, G4 * H_ / 4);
  k_split<<<(G4 * H_ / 4 + 255) / 256, 256, 0, stream>>>(Wh1, Wh1h, Wh1l, G4 * H_ / 4);
  k_addvec<<<16, 256, 0, stream>>>(b10i, b10h, bs0, G4);
  k_addvec<<<16, 256, 0, stream>>>(b11i, b11h, bs1, G4);
  k_addvec<<<16, 256, 0, stream>>>(b20i, b20h, bs2, G4);
  k_addvec<<<16, 256, 0, stream>>>(b21i, b21h, bs3, G4);
  hipMemsetAsync(ST, 0, stBytes, stream);

  dim3 gg(MC / 128, G4 / 128);
  const int pwBlocks = MC * H_ / 256;

  for (int c = 0; c < NCHUNK; ++c) {
    int t0 = c * TC;
    k_split_x<<<(MC * (D_ / 4) + 255) / 256, 256, 0, stream>>>(xx, XXh, XXl, t0);
    // l1 layer 0
    k_gemm3<<<gg, 256, 0, stream>>>(XXh, XXl, W10h, W10l, bs0, XG, MC, G4, D_, 0);
    k_pw<<<pwBlocks, 256, 0, stream>>>(XG, Aah, Aal);
    // l1 layer 1
    k_gemm3<<<gg, 256, 0, stream>>>(Aah, Aal, W11h, W11l, bs1, XG, MC, G4, H_, 0);
    k_pw<<<pwBlocks, 256, 0, stream>>>(XG, Abh, Abl);
    // l2 layer 0: gates (rec-layout, A b-major) then recurrence (ring = Ab)
    k_gemm3<<<gg, 256, 0, stream>>>(Abh, Abl, W20h, W20l, bs2, XG, MC, G4, H_, 1);
    k_rec<<<RBLK, 512, 0, stream>>>(XG, Wh0h, Wh0l, Abh, Abl, h00H, h00L, cb0,
                                    nullptr, FLG + (c * 2) * RBLK * 16, t0);
    // l2 layer 1: gates (A = ring, t-major) then recurrence (ring reused)
    k_gemm3<<<gg, 256, 0, stream>>>(Abh, Abl, W21h, W21l, bs3, XG, MC, G4, H_, 2);
    k_rec<<<RBLK, 512, 0, stream>>>(XG, Wh1h, Wh1l, Abh, Abl, h01H, h01L, cb1,
                                    FH, FLG + (c * 2 + 1) * RBLK * 16, t0);
  }

  // MLP
  k_fc<<<dim3(B_, 4), 256, 0, stream>>>(FH, mW1, mb1, Z1, H_, H_, 1);
  k_fc<<<dim3(B_, 2), 256, 0, stream>>>(Z1, mW2, mb2, Z2, H_, 512, 1);
  k_out<<<B_, 64, 0, stream>>>(Z2, mW3, mb3, (float*)d_out);
}